// Round 13
// baseline (1015.517 us; speedup 1.0000x reference)
//
#include <hip/hip_runtime.h>

typedef unsigned short ushort_t;
typedef __attribute__((ext_vector_type(8))) __bf16 bf16x8;
typedef __attribute__((ext_vector_type(4))) float f32x4;

#define NB 4
#define NL 4096
#define ND 1024
#define NH 16
#define NDH 64
#define NM (NB*NL)   // 16384

__device__ __forceinline__ ushort_t f2bf(float f) {
  unsigned u = __builtin_bit_cast(unsigned, f);
  u += 0x7fffu + ((u >> 16) & 1u);
  return (ushort_t)(u >> 16);
}

__device__ __forceinline__ void gl_lds16(const void* g, void* l) {
  __builtin_amdgcn_global_load_lds(
      (const __attribute__((address_space(1))) unsigned*)g,
      (__attribute__((address_space(3))) unsigned*)l, 16, 0, 0);
}

// ---------------- fused fp32 -> bf16 conversion (all 4 tensors) ----------------
__global__ __launch_bounds__(256) void k_cvt4(
    const float* __restrict__ x, const float* __restrict__ Wq,
    const float* __restrict__ Wkv, const float* __restrict__ Wout,
    ushort_t* __restrict__ xb, ushort_t* __restrict__ Wcat,
    ushort_t* __restrict__ Woutb)
{
  int i = blockIdx.x * 256 + threadIdx.x;
  const int stride = gridDim.x * 256;
  for (; i < 5242880; i += stride) {
    const float4* src; ushort4* dst; int off;
    if (i < 4194304)      { src = (const float4*)x;    dst = (ushort4*)xb;                 off = i; }
    else if (i < 4456448) { src = (const float4*)Wq;   dst = (ushort4*)Wcat;               off = i - 4194304; }
    else if (i < 4980736) { src = (const float4*)Wkv;  dst = (ushort4*)(Wcat + 1048576);   off = i - 4456448; }
    else                  { src = (const float4*)Wout; dst = (ushort4*)Woutb;              off = i - 4980736; }
    float4 v = src[off];
    ushort4 o;
    o.x = f2bf(v.x); o.y = f2bf(v.y); o.z = f2bf(v.z); o.w = f2bf(v.w);
    dst[off] = o;
  }
}

// ---------------- 256x256 GEMM, BK=64, K=1024 ----------------
// SBUF=1: single-buffered LDS (64KB) -> 2 blocks/CU; exposed per-tile stage is
//         covered by the co-resident block's MFMA burst (m114 cross-block overlap).
// SBUF=0: round-10 double-buffered schedule (1 block/CU), proven at 128.6us.
// MODE 0: C bf16 row-major.  MODE 2: C fp32 row-major.
template<int MODE, int SBUF>
__global__ __launch_bounds__(512, SBUF ? 4 : 2) void k_gemm256(
    const ushort_t* __restrict__ A, const ushort_t* __restrict__ Bt,
    void* __restrict__ Cout, int N, int gridN)
{
  __shared__ __align__(16) ushort_t As[(SBUF ? 1 : 2) * 16384];
  __shared__ __align__(16) ushort_t Bs[(SBUF ? 1 : 2) * 16384];
  constexpr int K = 1024;
  const int tid = threadIdx.x;
  const int lane = tid & 63, wv = tid >> 6;
  const int wm = wv >> 2, wn = wv & 3;        // 2x4 wave grid, wave tile 128x64
  const int l15 = lane & 15, lhi = lane >> 4;

  // T1 XCD chunking + within-XCD 4x4 supertile walk (round-8 map, passed)
  const int nb = gridDim.x * gridDim.y;
  const int lid = blockIdx.y * gridDim.x + blockIdx.x;
  const int perx = nb >> 3;
  const int xcd = lid & 7, l = lid >> 3;
  const int stC = gridN >> 2;
  const int st = l >> 4, wi = l & 15;
  const int rp = xcd * (perx / gridN) + (st / stC) * 4 + (wi >> 2);
  const int cp = (st % stC) * 4 + (wi & 3);
  const int rowBase = rp * 256;
  const int colBase = cp * 256;

  const ushort_t* Abase = A + (size_t)rowBase * K;
  const ushort_t* Bbase = Bt + (size_t)colBase * K;

  // staging: thread stages row so = tid>>3 (+64/chunk), 8 elems at scol.
  // LDS[row][sc] = G[row][sc ^ ((row&7)<<3)]  (inverse swizzle on source)
  const int so = tid >> 3;
  const int scol = (tid & 7) * 8;
  const int ssw = (so & 7) << 3;
  const int offG = so * K + (scol ^ ssw);
  const int sbase = wv * 512;

#define STAGE(dst, KT) do { \
  const ushort_t* Ag = Abase + (KT)*64 + offG; \
  const ushort_t* Bg = Bbase + (KT)*64 + offG; \
  gl_lds16(Ag,          &As[(dst)*16384 + sbase]); \
  gl_lds16(Ag + 65536,  &As[(dst)*16384 + 4096  + sbase]); \
  gl_lds16(Ag + 131072, &As[(dst)*16384 + 8192  + sbase]); \
  gl_lds16(Ag + 196608, &As[(dst)*16384 + 12288 + sbase]); \
  gl_lds16(Bg,          &Bs[(dst)*16384 + sbase]); \
  gl_lds16(Bg + 65536,  &Bs[(dst)*16384 + 4096  + sbase]); \
  gl_lds16(Bg + 131072, &Bs[(dst)*16384 + 8192  + sbase]); \
  gl_lds16(Bg + 196608, &Bs[(dst)*16384 + 12288 + sbase]); \
} while(0)

  const int fsw = (l15 & 7) << 3;
  const int kc0 = (lhi * 8) ^ fsw;             // swizzled read cols, K32 half 0
  const int kc1 = (32 + lhi * 8) ^ fsw;        // half 1

  f32x4 acc[8][4] = {};

#define HALF(CUR, KC) do { \
  bf16x8 af[8], bfr[4]; \
  _Pragma("unroll") for (int i_ = 0; i_ < 8; ++i_) \
    af[i_] = *(const bf16x8*)&As[(CUR)*16384 + (wm*128 + i_*16 + l15)*64 + (KC)]; \
  _Pragma("unroll") for (int j_ = 0; j_ < 4; ++j_) \
    bfr[j_] = *(const bf16x8*)&Bs[(CUR)*16384 + (wn*64 + j_*16 + l15)*64 + (KC)]; \
  __builtin_amdgcn_sched_barrier(0); \
  __builtin_amdgcn_s_setprio(1); \
  _Pragma("unroll") for (int i_ = 0; i_ < 8; ++i_) \
  _Pragma("unroll") for (int j_ = 0; j_ < 4; ++j_) \
    acc[i_][j_] = __builtin_amdgcn_mfma_f32_16x16x32_bf16(af[i_], bfr[j_], acc[i_][j_], 0, 0, 0); \
  __builtin_amdgcn_s_setprio(0); \
} while(0)

  if constexpr (SBUF) {
    // single buffer: stage -> drain -> compute -> barrier -> stage(next)
    STAGE(0, 0);
    asm volatile("s_waitcnt vmcnt(0)" ::: "memory");
    __builtin_amdgcn_s_barrier();
    for (int t = 0; t < 16; ++t) {
      HALF(0, kc0);
      HALF(0, kc1);
      if (t < 15) {
        __builtin_amdgcn_s_barrier();            // all reads of tile t retired
        STAGE(0, t + 1);
        asm volatile("s_waitcnt vmcnt(0)" ::: "memory");
        __builtin_amdgcn_s_barrier();            // DMA visible to all waves
      }
    }
  } else {
    // round-10 double-buffered schedule (proven)
    STAGE(0, 0);
    asm volatile("s_waitcnt vmcnt(0)" ::: "memory");
    __builtin_amdgcn_s_barrier();
    for (int t = 0; t < 16; ++t) {
      const int cur = t & 1;
      if (t < 15) STAGE(cur ^ 1, t + 1);
      HALF(cur, kc0);
      HALF(cur, kc1);
      if (t < 15) {
        asm volatile("s_waitcnt vmcnt(0)" ::: "memory");
        __builtin_amdgcn_s_barrier();
      }
    }
  }
#undef HALF
#undef STAGE

  // epilogue: C/D layout col = lane&15, row = (lane>>4)*4 + rr (probe-verified)
  const int orow = rowBase + wm * 128 + lhi * 4;
  const int ocol = colBase + wn * 64 + l15;
#pragma unroll
  for (int i = 0; i < 8; ++i)
#pragma unroll
    for (int j = 0; j < 4; ++j)
#pragma unroll
      for (int rr = 0; rr < 4; ++rr) {
        int gr = orow + i * 16 + rr;
        int gc = ocol + j * 16;
        if (MODE == 2) ((float*)Cout)[(size_t)gr * N + gc] = acc[i][j][rr];
        else           ((ushort_t*)Cout)[(size_t)gr * N + gc] = f2bf(acc[i][j][rr]);
      }
}

// ---------------- per-token attention over HEADS (unchanged, verified) ----------------
__global__ __launch_bounds__(256) void k_attn(
    const ushort_t* __restrict__ qkv, ushort_t* __restrict__ aout)
{
  __shared__ __align__(16) ushort_t qs[4][16*72];
  __shared__ __align__(16) ushort_t kvs[4][16*136];
  __shared__ __align__(16) ushort_t ps[4][16*40];
  __shared__ __align__(16) ushort_t os[4][1024];
  const int tid = threadIdx.x, lane = tid & 63, wave = tid >> 6;
  const int t = blockIdx.x * 4 + wave;
  const int l15 = lane & 15, lhi = lane >> 4;
  const ushort_t* row = qkv + (size_t)t * 3072;

#pragma unroll
  for (int c = 0; c < 6; ++c) {
    int c8 = c * 64 + lane;
    bf16x8 v = *(const bf16x8*)(row + c8 * 8);
    if (c8 < 128) {
      int h = c8 >> 3, off = (c8 & 7) * 8;
      *(bf16x8*)&qs[wave][h*72 + off] = v;
    } else {
      int e = c8 * 8 - 1024;
      int h = e >> 7, off = e & 127;
      *(bf16x8*)&kvs[wave][h*136 + off] = v;
    }
  }
  if (lane < 16) {
    bf16x8 z = {};
    *(bf16x8*)&ps[wave][lane*40 + 16] = z;
    *(bf16x8*)&ps[wave][lane*40 + 24] = z;
  }
  __syncthreads();

  bf16x8 aq0 = *(const bf16x8*)&qs[wave][l15*72 + lhi*8];
  bf16x8 aq1 = *(const bf16x8*)&qs[wave][l15*72 + 32 + lhi*8];
  bf16x8 bk0 = *(const bf16x8*)&kvs[wave][l15*136 + lhi*8];
  bf16x8 bk1 = *(const bf16x8*)&kvs[wave][l15*136 + 32 + lhi*8];
  f32x4 s = {};
  s = __builtin_amdgcn_mfma_f32_16x16x32_bf16(aq0, bk0, s, 0, 0, 0);
  s = __builtin_amdgcn_mfma_f32_16x16x32_bf16(aq1, bk1, s, 0, 0, 0);

#pragma unroll
  for (int r = 0; r < 4; ++r) {
    float sv = s[r] * 0.125f;
    float tm = sv;
#pragma unroll
    for (int off = 1; off < 16; off <<= 1) tm = fmaxf(tm, __shfl_xor(tm, off, 64));
    float p = __expf(sv - tm);
    float rs = p;
#pragma unroll
    for (int off = 1; off < 16; off <<= 1) rs += __shfl_xor(rs, off, 64);
    p /= rs;
    ps[wave][(lhi*4 + r)*40 + l15] = f2bf(p);
  }
  __syncthreads();

  bf16x8 pa = *(const bf16x8*)&ps[wave][l15*40 + lhi*8];
#pragma unroll
  for (int dt = 0; dt < 4; ++dt) {
    bf16x8 vb;
#pragma unroll
    for (int i = 0; i < 8; ++i) {
      int j = (lhi*8 + i) & 15;
      vb[i] = __builtin_bit_cast(__bf16, kvs[wave][j*136 + 64 + dt*16 + l15]);
    }
    f32x4 o = {};
    o = __builtin_amdgcn_mfma_f32_16x16x32_bf16(pa, vb, o, 0, 0, 0);
#pragma unroll
    for (int r = 0; r < 4; ++r)
      os[wave][(lhi*4 + r)*64 + dt*16 + l15] = f2bf(o[r]);
  }
  __syncthreads();

  ushort_t* orow = aout + (size_t)t * 1024;
#pragma unroll
  for (int c = 0; c < 2; ++c) {
    int idx = (c*64 + lane) * 8;
    *(bf16x8*)(orow + idx) = *(const bf16x8*)&os[wave][idx];
  }
}

extern "C" void kernel_launch(void* const* d_in, const int* in_sizes, int n_in,
                              void* d_out, int out_size, void* d_ws, size_t ws_size,
                              hipStream_t stream) {
  const float* x    = (const float*)d_in[0];
  const float* Wq   = (const float*)d_in[1];
  const float* Wkv  = (const float*)d_in[2];
  const float* Wout = (const float*)d_in[3];
  float* out = (float*)d_out;

  ushort_t* ws    = (ushort_t*)d_ws;
  ushort_t* xb    = ws;                          // 16,777,216 elems (reused as aout)
  ushort_t* Wcat  = xb + 16777216;               // 3,145,728  (Wq ; Wkv)
  ushort_t* Woutb = Wcat + 3145728;              // 1,048,576
  ushort_t* qkv   = Woutb + 1048576;             // 50,331,648 ([M][3072])
  ushort_t* aout  = xb;                          // alias: xb dead after gemm1

  // fused fp32 -> bf16
  k_cvt4<<<2048, 256, 0, stream>>>(x, Wq, Wkv, Wout, xb, Wcat, Woutb);

  // QKV projection: [16384 x 1024] x [3072 x 1024]^T -> qkv row-major
  // single-buffered LDS -> 2 blocks/CU
  dim3 g1(12, 64);
  k_gemm256<0, 1><<<g1, 512, 0, stream>>>(xb, Wcat, qkv, 3072, 12);

  // per-token attention over heads
  k_attn<<<NM/4, 256, 0, stream>>>(qkv, aout);

  // output projection: [16384 x 1024] x [1024 x 1024]^T -> fp32 (dbuf path)
  dim3 g3(4, 64);
  k_gemm256<2, 0><<<g3, 512, 0, stream>>>(aout, Woutb, out, 1024, 4);
}

// Round 14
// 257.788 us; speedup vs baseline: 3.9393x; 3.9393x over previous
//
#include <hip/hip_runtime.h>

typedef unsigned short ushort_t;
typedef __attribute__((ext_vector_type(8))) __bf16 bf16x8;
typedef __attribute__((ext_vector_type(4))) float f32x4;

#define NB 4
#define NL 4096
#define ND 1024
#define NH 16
#define NDH 64
#define NM (NB*NL)   // 16384

__device__ __forceinline__ ushort_t f2bf(float f) {
  unsigned u = __builtin_bit_cast(unsigned, f);
  u += 0x7fffu + ((u >> 16) & 1u);
  return (ushort_t)(u >> 16);
}

__device__ __forceinline__ void gl_lds16(const void* g, void* l) {
  __builtin_amdgcn_global_load_lds(
      (const __attribute__((address_space(1))) unsigned*)g,
      (__attribute__((address_space(3))) unsigned*)l, 16, 0, 0);
}

// ---------------- fused fp32 -> bf16 conversion (all 4 tensors) ----------------
__global__ __launch_bounds__(256) void k_cvt4(
    const float* __restrict__ x, const float* __restrict__ Wq,
    const float* __restrict__ Wkv, const float* __restrict__ Wout,
    ushort_t* __restrict__ xb, ushort_t* __restrict__ Wcat,
    ushort_t* __restrict__ Woutb)
{
  int i = blockIdx.x * 256 + threadIdx.x;
  const int stride = gridDim.x * 256;
  for (; i < 5242880; i += stride) {
    const float4* src; ushort4* dst; int off;
    if (i < 4194304)      { src = (const float4*)x;    dst = (ushort4*)xb;                 off = i; }
    else if (i < 4456448) { src = (const float4*)Wq;   dst = (ushort4*)Wcat;               off = i - 4194304; }
    else if (i < 4980736) { src = (const float4*)Wkv;  dst = (ushort4*)(Wcat + 1048576);   off = i - 4456448; }
    else                  { src = (const float4*)Wout; dst = (ushort4*)Woutb;              off = i - 4980736; }
    float4 v = src[off];
    ushort4 o;
    o.x = f2bf(v.x); o.y = f2bf(v.y); o.z = f2bf(v.z); o.w = f2bf(v.w);
    dst[off] = o;
  }
}

// ---------------- 256x256 GEMM, BK=64, K=1024: 128x128 wave tiles -------------
// 4 waves (256 thr), wave tile 128x128 -> per-CU LDS reads/tile 192->128
// (24->16 KB per 2.1 MFLOP per wave): flips the kernel MFMA-bound.
// acc[8][8] f32x4 = 256 VGPR; launch_bounds(256,1) -> 1 wave/SIMD, no spill
// (budget ~344 < 512). Intra-wave read/MFMA overlap via compiler's
// fine-grained lgkmcnt (no sched_barrier). Schedule/LDS/swizzle = round-10.
// MODE 0: C bf16 row-major.  MODE 2: C fp32 row-major.
template<int MODE>
__global__ __launch_bounds__(256, 1) void k_gemm256(
    const ushort_t* __restrict__ A, const ushort_t* __restrict__ Bt,
    void* __restrict__ Cout, int N, int gridN)
{
  __shared__ __align__(16) ushort_t As[2][16384];
  __shared__ __align__(16) ushort_t Bs[2][16384];
  constexpr int K = 1024;
  const int tid = threadIdx.x;
  const int lane = tid & 63, wv = tid >> 6;   // 4 waves
  const int wm = wv >> 1, wn = wv & 1;        // 2x2 wave grid, wave tile 128x128
  const int l15 = lane & 15, lhi = lane >> 4;

  // T1 XCD chunking + within-XCD 4x4 supertile walk (round-8 map, passed)
  const int nb = gridDim.x * gridDim.y;
  const int lid = blockIdx.y * gridDim.x + blockIdx.x;
  const int perx = nb >> 3;
  const int xcd = lid & 7, l = lid >> 3;
  const int stC = gridN >> 2;
  const int st = l >> 4, wi = l & 15;
  const int rp = xcd * (perx / gridN) + (st / stC) * 4 + (wi >> 2);
  const int cp = (st % stC) * 4 + (wi & 3);
  const int rowBase = rp * 256;
  const int colBase = cp * 256;

  const ushort_t* Abase = A + (size_t)rowBase * K;
  const ushort_t* Bbase = Bt + (size_t)colBase * K;

  // staging: 8 chunks/operand; chunk c = rows [c*32, c*32+32).
  // thread stages row c*32 + (tid>>3), 8 elems at (tid&7)*8 (inverse-swizzled src).
  const int so = tid >> 3;                 // 0..31
  const int scol = (tid & 7) * 8;
  const int ssw = (so & 7) << 3;           // row&7 == so&7 (c*32 = 0 mod 8)
  const int offG = so * K + (scol ^ ssw);
  const int sbase = wv * 512;              // wave-uniform base within chunk (elems)

#define STAGE(dst, KT) do { \
  const ushort_t* Ag = Abase + (KT)*64 + offG; \
  const ushort_t* Bg = Bbase + (KT)*64 + offG; \
  _Pragma("unroll") for (int c_ = 0; c_ < 8; ++c_) { \
    gl_lds16(Ag + c_*32*K, &As[dst][c_*2048 + sbase]); \
    gl_lds16(Bg + c_*32*K, &Bs[dst][c_*2048 + sbase]); \
  } \
} while(0)

  const int fsw = (l15 & 7) << 3;
  const int kc0 = (lhi * 8) ^ fsw;             // swizzled read cols, K32 half 0
  const int kc1 = (32 + lhi * 8) ^ fsw;        // half 1

  f32x4 acc[8][8] = {};

#define HALF(CUR, KC) do { \
  bf16x8 af[8], bfr[8]; \
  _Pragma("unroll") for (int i_ = 0; i_ < 8; ++i_) \
    af[i_] = *(const bf16x8*)&As[CUR][(wm*128 + i_*16 + l15)*64 + (KC)]; \
  _Pragma("unroll") for (int j_ = 0; j_ < 8; ++j_) \
    bfr[j_] = *(const bf16x8*)&Bs[CUR][(wn*128 + j_*16 + l15)*64 + (KC)]; \
  _Pragma("unroll") for (int i_ = 0; i_ < 8; ++i_) \
  _Pragma("unroll") for (int j_ = 0; j_ < 8; ++j_) \
    acc[i_][j_] = __builtin_amdgcn_mfma_f32_16x16x32_bf16(af[i_], bfr[j_], acc[i_][j_], 0, 0, 0); \
} while(0)

  // prologue
  STAGE(0, 0);
  asm volatile("s_waitcnt vmcnt(0)" ::: "memory");
  __builtin_amdgcn_s_barrier();

  for (int t = 0; t < 16; ++t) {
    const int cur = t & 1;
    if (t < 15) STAGE(cur ^ 1, t + 1);
    HALF(cur, kc0);
    HALF(cur, kc1);
    if (t < 15) {
      asm volatile("s_waitcnt vmcnt(0)" ::: "memory");
      __builtin_amdgcn_s_barrier();
    }
  }
#undef HALF
#undef STAGE

  // epilogue: C/D layout col = lane&15, row = (lane>>4)*4 + rr (probe-verified)
  const int orow = rowBase + wm * 128 + lhi * 4;
  const int ocol = colBase + wn * 128 + l15;
#pragma unroll
  for (int i = 0; i < 8; ++i)
#pragma unroll
    for (int j = 0; j < 8; ++j)
#pragma unroll
      for (int rr = 0; rr < 4; ++rr) {
        int gr = orow + i * 16 + rr;
        int gc = ocol + j * 16;
        if (MODE == 2) ((float*)Cout)[(size_t)gr * N + gc] = acc[i][j][rr];
        else           ((ushort_t*)Cout)[(size_t)gr * N + gc] = f2bf(acc[i][j][rr]);
      }
}

// ---------------- per-token attention over HEADS (unchanged, verified) ----------------
__global__ __launch_bounds__(256) void k_attn(
    const ushort_t* __restrict__ qkv, ushort_t* __restrict__ aout)
{
  __shared__ __align__(16) ushort_t qs[4][16*72];
  __shared__ __align__(16) ushort_t kvs[4][16*136];
  __shared__ __align__(16) ushort_t ps[4][16*40];
  __shared__ __align__(16) ushort_t os[4][1024];
  const int tid = threadIdx.x, lane = tid & 63, wave = tid >> 6;
  const int t = blockIdx.x * 4 + wave;
  const int l15 = lane & 15, lhi = lane >> 4;
  const ushort_t* row = qkv + (size_t)t * 3072;

#pragma unroll
  for (int c = 0; c < 6; ++c) {
    int c8 = c * 64 + lane;
    bf16x8 v = *(const bf16x8*)(row + c8 * 8);
    if (c8 < 128) {
      int h = c8 >> 3, off = (c8 & 7) * 8;
      *(bf16x8*)&qs[wave][h*72 + off] = v;
    } else {
      int e = c8 * 8 - 1024;
      int h = e >> 7, off = e & 127;
      *(bf16x8*)&kvs[wave][h*136 + off] = v;
    }
  }
  if (lane < 16) {
    bf16x8 z = {};
    *(bf16x8*)&ps[wave][lane*40 + 16] = z;
    *(bf16x8*)&ps[wave][lane*40 + 24] = z;
  }
  __syncthreads();

  bf16x8 aq0 = *(const bf16x8*)&qs[wave][l15*72 + lhi*8];
  bf16x8 aq1 = *(const bf16x8*)&qs[wave][l15*72 + 32 + lhi*8];
  bf16x8 bk0 = *(const bf16x8*)&kvs[wave][l15*136 + lhi*8];
  bf16x8 bk1 = *(const bf16x8*)&kvs[wave][l15*136 + 32 + lhi*8];
  f32x4 s = {};
  s = __builtin_amdgcn_mfma_f32_16x16x32_bf16(aq0, bk0, s, 0, 0, 0);
  s = __builtin_amdgcn_mfma_f32_16x16x32_bf16(aq1, bk1, s, 0, 0, 0);

#pragma unroll
  for (int r = 0; r < 4; ++r) {
    float sv = s[r] * 0.125f;
    float tm = sv;
#pragma unroll
    for (int off = 1; off < 16; off <<= 1) tm = fmaxf(tm, __shfl_xor(tm, off, 64));
    float p = __expf(sv - tm);
    float rs = p;
#pragma unroll
    for (int off = 1; off < 16; off <<= 1) rs += __shfl_xor(rs, off, 64);
    p /= rs;
    ps[wave][(lhi*4 + r)*40 + l15] = f2bf(p);
  }
  __syncthreads();

  bf16x8 pa = *(const bf16x8*)&ps[wave][l15*40 + lhi*8];
#pragma unroll
  for (int dt = 0; dt < 4; ++dt) {
    bf16x8 vb;
#pragma unroll
    for (int i = 0; i < 8; ++i) {
      int j = (lhi*8 + i) & 15;
      vb[i] = __builtin_bit_cast(__bf16, kvs[wave][j*136 + 64 + dt*16 + l15]);
    }
    f32x4 o = {};
    o = __builtin_amdgcn_mfma_f32_16x16x32_bf16(pa, vb, o, 0, 0, 0);
#pragma unroll
    for (int r = 0; r < 4; ++r)
      os[wave][(lhi*4 + r)*64 + dt*16 + l15] = f2bf(o[r]);
  }
  __syncthreads();

  ushort_t* orow = aout + (size_t)t * 1024;
#pragma unroll
  for (int c = 0; c < 2; ++c) {
    int idx = (c*64 + lane) * 8;
    *(bf16x8*)(orow + idx) = *(const bf16x8*)&os[wave][idx];
  }
}

extern "C" void kernel_launch(void* const* d_in, const int* in_sizes, int n_in,
                              void* d_out, int out_size, void* d_ws, size_t ws_size,
                              hipStream_t stream) {
  const float* x    = (const float*)d_in[0];
  const float* Wq   = (const float*)d_in[1];
  const float* Wkv  = (const float*)d_in[2];
  const float* Wout = (const float*)d_in[3];
  float* out = (float*)d_out;

  ushort_t* ws    = (ushort_t*)d_ws;
  ushort_t* xb    = ws;                          // 16,777,216 elems (reused as aout)
  ushort_t* Wcat  = xb + 16777216;               // 3,145,728  (Wq ; Wkv)
  ushort_t* Woutb = Wcat + 3145728;              // 1,048,576
  ushort_t* qkv   = Woutb + 1048576;             // 50,331,648 ([M][3072])
  ushort_t* aout  = xb;                          // alias: xb dead after gemm1

  // fused fp32 -> bf16
  k_cvt4<<<2048, 256, 0, stream>>>(x, Wq, Wkv, Wout, xb, Wcat, Woutb);

  // QKV projection: [16384 x 1024] x [3072 x 1024]^T -> qkv row-major
  dim3 g1(12, 64);
  k_gemm256<0><<<g1, 256, 0, stream>>>(xb, Wcat, qkv, 3072, 12);

  // per-token attention over heads
  k_attn<<<NM/4, 256, 0, stream>>>(qkv, aout);

  // output projection: [16384 x 1024] x [1024 x 1024]^T -> fp32
  dim3 g3(4, 64);
  k_gemm256<2><<<g3, 256, 0, stream>>>(aout, Woutb, out, 1024, 4);
}

// Round 15
// 192.020 us; speedup vs baseline: 5.2886x; 1.3425x over previous
//
#include <hip/hip_runtime.h>

typedef unsigned short ushort_t;
typedef __attribute__((ext_vector_type(8))) __bf16 bf16x8;
typedef __attribute__((ext_vector_type(4))) float f32x4;

#define NB 4
#define NL 4096
#define ND 1024
#define NH 16
#define NDH 64
#define NM (NB*NL)   // 16384

__device__ __forceinline__ ushort_t f2bf(float f) {
  unsigned u = __builtin_bit_cast(unsigned, f);
  u += 0x7fffu + ((u >> 16) & 1u);
  return (ushort_t)(u >> 16);
}

__device__ __forceinline__ void gl_lds16(const void* g, void* l) {
  __builtin_amdgcn_global_load_lds(
      (const __attribute__((address_space(1))) unsigned*)g,
      (__attribute__((address_space(3))) unsigned*)l, 16, 0, 0);
}

// ---------------- fused fp32 -> bf16 conversion (all 4 tensors) ----------------
__global__ __launch_bounds__(256) void k_cvt4(
    const float* __restrict__ x, const float* __restrict__ Wq,
    const float* __restrict__ Wkv, const float* __restrict__ Wout,
    ushort_t* __restrict__ xb, ushort_t* __restrict__ Wcat,
    ushort_t* __restrict__ Woutb)
{
  int i = blockIdx.x * 256 + threadIdx.x;
  const int stride = gridDim.x * 256;
  for (; i < 5242880; i += stride) {
    const float4* src; ushort4* dst; int off;
    if (i < 4194304)      { src = (const float4*)x;    dst = (ushort4*)xb;                 off = i; }
    else if (i < 4456448) { src = (const float4*)Wq;   dst = (ushort4*)Wcat;               off = i - 4194304; }
    else if (i < 4980736) { src = (const float4*)Wkv;  dst = (ushort4*)(Wcat + 1048576);   off = i - 4456448; }
    else                  { src = (const float4*)Wout; dst = (ushort4*)Woutb;              off = i - 4980736; }
    float4 v = src[off];
    ushort4 o;
    o.x = f2bf(v.x); o.y = f2bf(v.y); o.z = f2bf(v.z); o.w = f2bf(v.w);
    dst[off] = o;
  }
}

// ---------------- 256x256 GEMM, BK=64, K=1024: non-redundant-read schedule ----
// Round-10 configuration (best measured: GEMM1 128.6us, 802 TF).
// Per K-tile: each wave reads its FULL 128x64 operand set once (af[8]+bfr[4]
// per K32 half, 24 ds_read_b128/tile). 8 waves (2x4), 2 waves/SIMD.
// LDS: [256 rows][64 k] per operand, identity row map, T2 col-XOR swizzle
// (linear DMA dest + inverse-swizzled global source + swizzled ds_read).
template<int MODE>
__global__ __launch_bounds__(512, 2) void k_gemm256(
    const ushort_t* __restrict__ A, const ushort_t* __restrict__ Bt,
    void* __restrict__ Cout, int N, int gridN)
{
  __shared__ __align__(16) ushort_t As[2][16384];
  __shared__ __align__(16) ushort_t Bs[2][16384];
  constexpr int K = 1024;
  const int tid = threadIdx.x;
  const int lane = tid & 63, wv = tid >> 6;
  const int wm = wv >> 2, wn = wv & 3;        // 2x4 wave grid, wave tile 128x64
  const int l15 = lane & 15, lhi = lane >> 4;

  // T1 XCD chunking + within-XCD 4x4 supertile walk
  const int nb = gridDim.x * gridDim.y;
  const int lid = blockIdx.y * gridDim.x + blockIdx.x;
  const int perx = nb >> 3;
  const int xcd = lid & 7, l = lid >> 3;
  const int stC = gridN >> 2;
  const int st = l >> 4, wi = l & 15;
  const int rp = xcd * (perx / gridN) + (st / stC) * 4 + (wi >> 2);
  const int cp = (st % stC) * 4 + (wi & 3);
  const int rowBase = rp * 256;
  const int colBase = cp * 256;

  const ushort_t* Abase = A + (size_t)rowBase * K;
  const ushort_t* Bbase = Bt + (size_t)colBase * K;

  // staging: thread stages row so = tid>>3 (+64/chunk), 8 elems at scol.
  // LDS[row][sc] = G[row][sc ^ ((row&7)<<3)]  (inverse swizzle on source)
  const int so = tid >> 3;
  const int scol = (tid & 7) * 8;
  const int ssw = (so & 7) << 3;
  const int offG = so * K + (scol ^ ssw);
  const int sbase = wv * 512;

#define STAGE(dst, KT) do { \
  const ushort_t* Ag = Abase + (KT)*64 + offG; \
  const ushort_t* Bg = Bbase + (KT)*64 + offG; \
  gl_lds16(Ag,          &As[dst][sbase]); \
  gl_lds16(Ag + 65536,  &As[dst][4096  + sbase]); \
  gl_lds16(Ag + 131072, &As[dst][8192  + sbase]); \
  gl_lds16(Ag + 196608, &As[dst][12288 + sbase]); \
  gl_lds16(Bg,          &Bs[dst][sbase]); \
  gl_lds16(Bg + 65536,  &Bs[dst][4096  + sbase]); \
  gl_lds16(Bg + 131072, &Bs[dst][8192  + sbase]); \
  gl_lds16(Bg + 196608, &Bs[dst][12288 + sbase]); \
} while(0)

  const int fsw = (l15 & 7) << 3;
  const int kc0 = (lhi * 8) ^ fsw;             // swizzled read cols, K32 half 0
  const int kc1 = (32 + lhi * 8) ^ fsw;        // half 1

  f32x4 acc[8][4] = {};

#define HALF(CUR, KC) do { \
  bf16x8 af[8], bfr[4]; \
  _Pragma("unroll") for (int i_ = 0; i_ < 8; ++i_) \
    af[i_] = *(const bf16x8*)&As[CUR][(wm*128 + i_*16 + l15)*64 + (KC)]; \
  _Pragma("unroll") for (int j_ = 0; j_ < 4; ++j_) \
    bfr[j_] = *(const bf16x8*)&Bs[CUR][(wn*64 + j_*16 + l15)*64 + (KC)]; \
  __builtin_amdgcn_sched_barrier(0); \
  __builtin_amdgcn_s_setprio(1); \
  _Pragma("unroll") for (int i_ = 0; i_ < 8; ++i_) \
  _Pragma("unroll") for (int j_ = 0; j_ < 4; ++j_) \
    acc[i_][j_] = __builtin_amdgcn_mfma_f32_16x16x32_bf16(af[i_], bfr[j_], acc[i_][j_], 0, 0, 0); \
  __builtin_amdgcn_s_setprio(0); \
} while(0)

  // prologue
  STAGE(0, 0);
  asm volatile("s_waitcnt vmcnt(0)" ::: "memory");
  __builtin_amdgcn_s_barrier();

  for (int t = 0; t < 16; ++t) {
    const int cur = t & 1;
    if (t < 15) STAGE(cur ^ 1, t + 1);
    HALF(cur, kc0);
    HALF(cur, kc1);
    if (t < 15) {
      asm volatile("s_waitcnt vmcnt(0)" ::: "memory");
      __builtin_amdgcn_s_barrier();
    }
  }
#undef HALF
#undef STAGE

  // epilogue: C/D layout col = lane&15, row = (lane>>4)*4 + rr (probe-verified)
  const int orow = rowBase + wm * 128 + lhi * 4;
  const int ocol = colBase + wn * 64 + l15;
#pragma unroll
  for (int i = 0; i < 8; ++i)
#pragma unroll
    for (int j = 0; j < 4; ++j)
#pragma unroll
      for (int rr = 0; rr < 4; ++rr) {
        int gr = orow + i * 16 + rr;
        int gc = ocol + j * 16;
        if (MODE == 2) ((float*)Cout)[(size_t)gr * N + gc] = acc[i][j][rr];
        else           ((ushort_t*)Cout)[(size_t)gr * N + gc] = f2bf(acc[i][j][rr]);
      }
}

// ---------------- per-token attention over HEADS (unchanged, verified) ----------------
__global__ __launch_bounds__(256) void k_attn(
    const ushort_t* __restrict__ qkv, ushort_t* __restrict__ aout)
{
  __shared__ __align__(16) ushort_t qs[4][16*72];
  __shared__ __align__(16) ushort_t kvs[4][16*136];
  __shared__ __align__(16) ushort_t ps[4][16*40];
  __shared__ __align__(16) ushort_t os[4][1024];
  const int tid = threadIdx.x, lane = tid & 63, wave = tid >> 6;
  const int t = blockIdx.x * 4 + wave;
  const int l15 = lane & 15, lhi = lane >> 4;
  const ushort_t* row = qkv + (size_t)t * 3072;

#pragma unroll
  for (int c = 0; c < 6; ++c) {
    int c8 = c * 64 + lane;
    bf16x8 v = *(const bf16x8*)(row + c8 * 8);
    if (c8 < 128) {
      int h = c8 >> 3, off = (c8 & 7) * 8;
      *(bf16x8*)&qs[wave][h*72 + off] = v;
    } else {
      int e = c8 * 8 - 1024;
      int h = e >> 7, off = e & 127;
      *(bf16x8*)&kvs[wave][h*136 + off] = v;
    }
  }
  if (lane < 16) {
    bf16x8 z = {};
    *(bf16x8*)&ps[wave][lane*40 + 16] = z;
    *(bf16x8*)&ps[wave][lane*40 + 24] = z;
  }
  __syncthreads();

  bf16x8 aq0 = *(const bf16x8*)&qs[wave][l15*72 + lhi*8];
  bf16x8 aq1 = *(const bf16x8*)&qs[wave][l15*72 + 32 + lhi*8];
  bf16x8 bk0 = *(const bf16x8*)&kvs[wave][l15*136 + lhi*8];
  bf16x8 bk1 = *(const bf16x8*)&kvs[wave][l15*136 + 32 + lhi*8];
  f32x4 s = {};
  s = __builtin_amdgcn_mfma_f32_16x16x32_bf16(aq0, bk0, s, 0, 0, 0);
  s = __builtin_amdgcn_mfma_f32_16x16x32_bf16(aq1, bk1, s, 0, 0, 0);

#pragma unroll
  for (int r = 0; r < 4; ++r) {
    float sv = s[r] * 0.125f;
    float tm = sv;
#pragma unroll
    for (int off = 1; off < 16; off <<= 1) tm = fmaxf(tm, __shfl_xor(tm, off, 64));
    float p = __expf(sv - tm);
    float rs = p;
#pragma unroll
    for (int off = 1; off < 16; off <<= 1) rs += __shfl_xor(rs, off, 64);
    p /= rs;
    ps[wave][(lhi*4 + r)*40 + l15] = f2bf(p);
  }
  __syncthreads();

  bf16x8 pa = *(const bf16x8*)&ps[wave][l15*40 + lhi*8];
#pragma unroll
  for (int dt = 0; dt < 4; ++dt) {
    bf16x8 vb;
#pragma unroll
    for (int i = 0; i < 8; ++i) {
      int j = (lhi*8 + i) & 15;
      vb[i] = __builtin_bit_cast(__bf16, kvs[wave][j*136 + 64 + dt*16 + l15]);
    }
    f32x4 o = {};
    o = __builtin_amdgcn_mfma_f32_16x16x32_bf16(pa, vb, o, 0, 0, 0);
#pragma unroll
    for (int r = 0; r < 4; ++r)
      os[wave][(lhi*4 + r)*64 + dt*16 + l15] = f2bf(o[r]);
  }
  __syncthreads();

  ushort_t* orow = aout + (size_t)t * 1024;
#pragma unroll
  for (int c = 0; c < 2; ++c) {
    int idx = (c*64 + lane) * 8;
    *(bf16x8*)(orow + idx) = *(const bf16x8*)&os[wave][idx];
  }
}

extern "C" void kernel_launch(void* const* d_in, const int* in_sizes, int n_in,
                              void* d_out, int out_size, void* d_ws, size_t ws_size,
                              hipStream_t stream) {
  const float* x    = (const float*)d_in[0];
  const float* Wq   = (const float*)d_in[1];
  const float* Wkv  = (const float*)d_in[2];
  const float* Wout = (const float*)d_in[3];
  float* out = (float*)d_out;

  ushort_t* ws    = (ushort_t*)d_ws;
  ushort_t* xb    = ws;                          // 16,777,216 elems (reused as aout)
  ushort_t* Wcat  = xb + 16777216;               // 3,145,728  (Wq ; Wkv)
  ushort_t* Woutb = Wcat + 3145728;              // 1,048,576
  ushort_t* qkv   = Woutb + 1048576;             // 50,331,648 ([M][3072])
  ushort_t* aout  = xb;                          // alias: xb dead after gemm1

  // fused fp32 -> bf16
  k_cvt4<<<2048, 256, 0, stream>>>(x, Wq, Wkv, Wout, xb, Wcat, Woutb);

  // QKV projection: [16384 x 1024] x [3072 x 1024]^T -> qkv row-major
  dim3 g1(12, 64);
  k_gemm256<0><<<g1, 512, 0, stream>>>(xb, Wcat, qkv, 3072, 12);

  // per-token attention over heads
  k_attn<<<NM/4, 256, 0, stream>>>(qkv, aout);

  // output projection: [16384 x 1024] x [1024 x 1024]^T -> fp32
  dim3 g3(4, 64);
  k_gemm256<2><<<g3, 512, 0, stream>>>(aout, Woutb, out, 1024, 4);
}